// Round 11
// baseline (592.006 us; speedup 1.0000x reference)
//
#include <hip/hip_runtime.h>

#define N_NODES 100000
#define N_EDGES 3200000
#define N_GRAPHS 2048
#define VOCAB 92
#define H 64
#define N_LAYERS 3

#define BUCK_BITS 7
#define BUCK_NODES (1 << BUCK_BITS)                          // 128 nodes / bucket
#define NBUCK ((N_NODES + BUCK_NODES - 1) / BUCK_NODES)      // 782

#define PART_BLOCKS 256
#define EDGES_PER_PART (N_EDGES / PART_BLOCKS)               // 12500

#define LIN_NODES_PER_WAVE 32
#define G0_NODES_PER_WAVE 8

// fp32 -> bf16 (round-to-nearest-even)
__device__ inline unsigned short f2bf(float f) {
    union { float f; unsigned u; } v; v.f = f;
    unsigned u = v.u;
    u += 0x7fffu + ((u >> 16) & 1u);
    return (unsigned short)(u >> 16);
}
__device__ inline float bfhi(unsigned p) {
    union { unsigned u; float f; } v; v.u = p & 0xffff0000u; return v.f;
}
__device__ inline float bflo(unsigned p) {
    union { unsigned u; float f; } v; v.u = p << 16; return v.f;
}

// ---------------- kernels ----------------

// zero bucket counts and node degrees
__global__ void k_init(int* bcnt, int* degi) {
    int i = blockIdx.x * blockDim.x + threadIdx.x;
    if (i < NBUCK) bcnt[i] = 0;
    if (i < N_NODES) degi[i] = 0;
}

// bucket histogram; also store per-block rows for binA reuse
__global__ void k_bhist(const int* __restrict__ col, int* __restrict__ bcnt,
                        int* __restrict__ blkhist) {
    __shared__ int lh[NBUCK];
    int tid = threadIdx.x;
    for (int i = tid; i < NBUCK; i += 256) lh[i] = 0;
    __syncthreads();
    int base = blockIdx.x * EDGES_PER_PART;
    for (int k = tid; k < EDGES_PER_PART; k += 256)
        atomicAdd(&lh[col[base + k] >> BUCK_BITS], 1);
    __syncthreads();
    int* myhist = blkhist + (size_t)blockIdx.x * NBUCK;
    for (int i = tid; i < NBUCK; i += 256) {
        int c = lh[i];
        myhist[i] = c;
        if (c) atomicAdd(&bcnt[i], c);
    }
}

// scan the 782 bucket counts; init reservation cursors
__global__ void k_bscan(const int* __restrict__ bcnt, int* __restrict__ bbase,
                        int* __restrict__ bcur) {
    __shared__ int s[1024];
    int tid = threadIdx.x;
    int v = (tid < NBUCK) ? bcnt[tid] : 0;
    s[tid] = v;
    __syncthreads();
    for (int off = 1; off < 1024; off <<= 1) {
        int x = (tid >= off) ? s[tid - off] : 0;
        __syncthreads();
        s[tid] += x;
        __syncthreads();
    }
    if (tid < NBUCK) {
        int e = s[tid] - v;
        bbase[tid] = e;
        bcur[tid] = e;
    }
    if (tid == 0) bbase[NBUCK] = N_EDGES;
}

// pass A: slice reservation from precomputed block hist, rank + packed write,
// plus global node-degree accumulation (frees binB of its histogram pass)
__global__ __launch_bounds__(1024) void k_binA(const int* __restrict__ row,
                                               const int* __restrict__ col,
                                               const int* __restrict__ blkhist,
                                               int* __restrict__ bcur,
                                               int* __restrict__ staging,
                                               int* __restrict__ degi) {
    __shared__ int lcnt[NBUCK];
    __shared__ int lbase[NBUCK];
    int tid = threadIdx.x;
    int base = blockIdx.x * EDGES_PER_PART;
    const int* myhist = blkhist + (size_t)blockIdx.x * NBUCK;
    for (int i = tid; i < NBUCK; i += 1024) {
        int c = myhist[i];
        lbase[i] = c ? atomicAdd(&bcur[i], c) : 0;
        lcnt[i] = 0;
    }
    __syncthreads();
    for (int k = tid; k < EDGES_PER_PART; k += 1024) {
        int c = col[base + k];
        int b = c >> BUCK_BITS;
        int r = atomicAdd(&lcnt[b], 1);
        staging[lbase[b] + r] = row[base + k] | ((c & (BUCK_NODES - 1)) << 17);
        atomicAdd(&degi[c], 1);
    }
}

// per-bucket: scan degrees -> row_start; dinv; packed(x, dinv_bf16)
__global__ void k_nodeinit(const int* __restrict__ degi, const int* __restrict__ bbase,
                           const int* __restrict__ x, int* __restrict__ row_start,
                           float* __restrict__ dinv, unsigned* __restrict__ packed) {
    __shared__ int s[BUCK_NODES];
    int b = blockIdx.x, tid = threadIdx.x;
    int n = (b << BUCK_BITS) + tid;
    int d = (n < N_NODES) ? degi[n] : 0;
    s[tid] = d;
    __syncthreads();
    for (int off = 1; off < BUCK_NODES; off <<= 1) {
        int v = (tid >= off) ? s[tid - off] : 0;
        __syncthreads();
        s[tid] += v;
        __syncthreads();
    }
    if (n < N_NODES) {
        int excl = s[tid] - d;
        row_start[n] = bbase[b] + excl;
        float dv = rsqrtf((float)(d + 1));
        dinv[n] = dv;
        packed[n] = ((unsigned)f2bf(dv) << 16) | (unsigned)x[n];
    }
}

// pass B: single scatter pass; also materializes the packed stream in edge order
__global__ void k_binB(const int* __restrict__ staging, const int* __restrict__ bbase,
                       const int* __restrict__ row_start, const unsigned* __restrict__ packed,
                       int* __restrict__ sorted_row, unsigned* __restrict__ sorted_pk) {
    __shared__ int lde[BUCK_NODES];
    __shared__ int lrs[BUCK_NODES];
    int b = blockIdx.x, tid = threadIdx.x;
    int n0 = b << BUCK_BITS;
    int s0 = bbase[b], s1 = bbase[b + 1];
    if (tid < BUCK_NODES) {
        lde[tid] = 0;
        int n = n0 + tid;
        lrs[tid] = (n < N_NODES) ? row_start[n] : 0;
    }
    __syncthreads();
    for (int i = s0 + tid; i < s1; i += 256) {
        int p = staging[i];
        int ln = p >> 17;
        int r = atomicAdd(&lde[ln], 1);
        int rw = p & 0x1FFFF;
        int pos = lrs[ln] + r;
        sorted_row[pos] = rw;
        sorted_pk[pos] = packed[rw];
    }
}

// M = emb @ W0 (92 x 64, f32). One block (64 threads) per vocab row.
__global__ void k_premix(const float* __restrict__ emb, const float* __restrict__ W0,
                         float* __restrict__ M) {
    int v = blockIdx.x, c = threadIdx.x;
    float acc = 0.0f;
#pragma unroll
    for (int k = 0; k < H; ++k) acc += emb[v * H + k] * W0[k * H + c];
    M[v * H + c] = acc;
}

// layer-0 gather: acc[n] = sum_e dinv_bf16[r] * M[x[r]], reading the sequential
// sorted_pk stream (no dependent loads). M staged in LDS as bf16x2 (11.75 KB).
__global__ __launch_bounds__(256) void k_gather0(const unsigned* __restrict__ sorted_pk,
                                                 const int* __restrict__ row_start,
                                                 const int* __restrict__ degi,
                                                 const unsigned* __restrict__ packed,
                                                 const float* __restrict__ M,
                                                 const float* __restrict__ dinv,
                                                 const float* __restrict__ bias,
                                                 float* __restrict__ h) {
    __shared__ unsigned Mb[VOCAB * 32];  // bf16x2 per (row, channel-pair)
    int tid = threadIdx.x;
    const float2* Mg = (const float2*)M;
    for (int i = tid; i < VOCAB * 32; i += 256) {
        float2 m = Mg[i];
        Mb[i] = ((unsigned)f2bf(m.y) << 16) | (unsigned)f2bf(m.x);
    }
    __syncthreads();
    int lane = tid & 63;
    int half = lane >> 5;
    int sub = lane & 31;
    int wid = (blockIdx.x * blockDim.x + tid) >> 6;
    int nbase = wid * G0_NODES_PER_WAVE;
    const float2* b2 = (const float2*)bias;
    float2 bb = b2[sub];
    float2* h2 = (float2*)h;
    for (int ni = 0; ni < G0_NODES_PER_WAVE; ++ni) {
        int n = nbase + ni;
        if (n >= N_NODES) break;
        int start = row_start[n];
        int d = degi[n];
        float ax = 0.0f, ay = 0.0f;
        int e = half;
        for (; e + 14 < d; e += 16) {
            unsigned p[8];
#pragma unroll
            for (int j = 0; j < 8; ++j) p[j] = sorted_pk[start + e + 2 * j];
#pragma unroll
            for (int j = 0; j < 8; ++j) {
                float dv = __uint_as_float(p[j] & 0xffff0000u);
                unsigned m = Mb[(p[j] & 127u) * 32 + sub];
                ax += dv * bflo(m); ay += dv * bfhi(m);
            }
        }
        for (; e + 6 < d; e += 8) {
            unsigned p[4];
#pragma unroll
            for (int j = 0; j < 4; ++j) p[j] = sorted_pk[start + e + 2 * j];
#pragma unroll
            for (int j = 0; j < 4; ++j) {
                float dv = __uint_as_float(p[j] & 0xffff0000u);
                unsigned m = Mb[(p[j] & 127u) * 32 + sub];
                ax += dv * bflo(m); ay += dv * bfhi(m);
            }
        }
        for (; e < d; e += 2) {
            unsigned p = sorted_pk[start + e];
            float dv = __uint_as_float(p & 0xffff0000u);
            unsigned m = Mb[(p & 127u) * 32 + sub];
            ax += dv * bflo(m); ay += dv * bfhi(m);
        }
        ax += __shfl_xor(ax, 32, 64);
        ay += __shfl_xor(ay, 32, 64);
        if (half == 0) {
            unsigned ps = packed[n];  // self-loop term
            float dvs = __uint_as_float(ps & 0xffff0000u);
            unsigned ms = Mb[(ps & 127u) * 32 + sub];
            ax += dvs * bflo(ms); ay += dvs * bfhi(ms);
            float di = dinv[n];
            h2[(size_t)n * 32 + sub] = make_float2(fmaxf(ax * di + bb.x, 0.0f),
                                                   fmaxf(ay * di + bb.y, 0.0f));
        }
    }
}

// t' = bf16( dinv[n] * (h @ W) )  (layers 1,2)
__global__ __launch_bounds__(256) void k_linear(const float* __restrict__ hin,
                                                const float* __restrict__ W,
                                                const float* __restrict__ dinv,
                                                unsigned short* __restrict__ t) {
    int lane = threadIdx.x & 63;
    int wid = (blockIdx.x * blockDim.x + threadIdx.x) >> 6;
    float wreg[H];
#pragma unroll
    for (int k = 0; k < H; ++k) wreg[k] = W[k * H + lane];
    int n0 = wid * LIN_NODES_PER_WAVE;
    if (n0 >= N_NODES) return;
    for (int i = 0; i < LIN_NODES_PER_WAVE; ++i) {
        int n = __builtin_amdgcn_readfirstlane(n0 + i);
        if (n >= N_NODES) break;
        const float* hr = hin + (size_t)n * H;
        float acc = 0.0f;
#pragma unroll
        for (int k = 0; k < H; ++k) acc += hr[k] * wreg[k];
        t[(size_t)n * H + lane] = f2bf(acc * dinv[n]);
    }
}

// layers 1-2 gather + finalize: one wave per node; 2 half-waves, bf16x2 channels
__global__ void k_gather(const int* __restrict__ sorted_row, const int* __restrict__ row_start,
                         const int* __restrict__ degi, const unsigned short* __restrict__ t,
                         const float* __restrict__ dinv, const float* __restrict__ bias,
                         float* __restrict__ h) {
    int gid = blockIdx.x * blockDim.x + threadIdx.x;
    int n = gid >> 6;
    if (n >= N_NODES) return;
    int lane = threadIdx.x & 63;
    int half = lane >> 5;
    int sub = lane & 31;
    const unsigned* t2 = (const unsigned*)t;
    int start = row_start[n];
    int d = degi[n];
    float ax = 0.0f, ay = 0.0f;
    int e = half;
    for (; e + 14 < d; e += 16) {
        unsigned p[8];
#pragma unroll
        for (int j = 0; j < 8; ++j)
            p[j] = t2[(size_t)sorted_row[start + e + 2 * j] * 32 + sub];
#pragma unroll
        for (int j = 0; j < 8; ++j) { ax += bflo(p[j]); ay += bfhi(p[j]); }
    }
    for (; e + 6 < d; e += 8) {
        unsigned p[4];
#pragma unroll
        for (int j = 0; j < 4; ++j)
            p[j] = t2[(size_t)sorted_row[start + e + 2 * j] * 32 + sub];
#pragma unroll
        for (int j = 0; j < 4; ++j) { ax += bflo(p[j]); ay += bfhi(p[j]); }
    }
    for (; e < d; e += 2) {
        unsigned p = t2[(size_t)sorted_row[start + e] * 32 + sub];
        ax += bflo(p); ay += bfhi(p);
    }
    ax += __shfl_xor(ax, 32, 64);
    ay += __shfl_xor(ay, 32, 64);
    if (half == 0) {
        unsigned self = t2[(size_t)n * 32 + sub];
        ax += bflo(self); ay += bfhi(self);
        float di = dinv[n];
        const float2* b2 = (const float2*)bias;
        float2 bb = b2[sub];
        float2* h2 = (float2*)h;
        float2 hp = h2[(size_t)n * 32 + sub];  // residual (layers 1,2 only)
        float vx = hp.x + fmaxf(ax * di + bb.x, 0.0f);
        float vy = hp.y + fmaxf(ay * di + bb.y, 0.0f);
        h2[(size_t)n * 32 + sub] = make_float2(vx, vy);
    }
}

// fused mean-pool + MLP: one wave per graph (batch sorted -> binary search)
__global__ void k_poolmlp(const float* __restrict__ h, const int* __restrict__ batch,
                          const float* __restrict__ w1, const float* __restrict__ b1,
                          const float* __restrict__ w2, const float* __restrict__ b2,
                          const float* __restrict__ w3, const float* __restrict__ b3,
                          float* __restrict__ out) {
    __shared__ float sg[H];
    __shared__ float s1[32];
    __shared__ float s2[16];
    int g = blockIdx.x, tid = threadIdx.x;
    int lo = 0, hi = N_NODES;
    while (lo < hi) { int mid = (lo + hi) >> 1; if (batch[mid] < g) lo = mid + 1; else hi = mid; }
    int lo2 = lo, hi2 = N_NODES;
    while (lo2 < hi2) { int mid = (lo2 + hi2) >> 1; if (batch[mid] < g + 1) lo2 = mid + 1; else hi2 = mid; }
    float acc = 0.0f;
    for (int n = lo; n < lo2; ++n) acc += h[(size_t)n * H + tid];
    float cntf = (float)(lo2 - lo);
    sg[tid] = acc / fmaxf(cntf, 1.0f);
    __syncthreads();
    if (tid < 32) {
        float a = b1[tid];
#pragma unroll
        for (int k = 0; k < H; ++k) a += sg[k] * w1[k * 32 + tid];
        s1[tid] = fmaxf(a, 0.0f);
    }
    __syncthreads();
    if (tid < 16) {
        float a = b2[tid];
#pragma unroll
        for (int k = 0; k < 32; ++k) a += s1[k] * w2[k * 16 + tid];
        s2[tid] = fmaxf(a, 0.0f);
    }
    __syncthreads();
    if (tid == 0) {
        float a = b3[0];
#pragma unroll
        for (int k = 0; k < 16; ++k) a += s2[k] * w3[k];
        out[g] = a;
    }
}

// ---------------- launch ----------------

extern "C" void kernel_launch(void* const* d_in, const int* in_sizes, int n_in,
                              void* d_out, int out_size, void* d_ws, size_t ws_size,
                              hipStream_t stream) {
    const int*   x      = (const int*)d_in[0];
    const int*   eidx   = (const int*)d_in[1];   // (2, E): row = eidx, col = eidx + E
    const int*   batch  = (const int*)d_in[2];
    const float* emb    = (const float*)d_in[3];
    const float* conv_w = (const float*)d_in[4];
    const float* conv_b = (const float*)d_in[5];
    const float* w1     = (const float*)d_in[6];
    const float* b1     = (const float*)d_in[7];
    const float* w2     = (const float*)d_in[8];
    const float* b2     = (const float*)d_in[9];
    const float* w3     = (const float*)d_in[10];
    const float* b3     = (const float*)d_in[11];
    float* out = (float*)d_out;

    const int* row = eidx;
    const int* col = eidx + N_EDGES;

    // workspace layout (4-byte units)
    char* wsb = (char*)d_ws;
    size_t off = 0;
    auto alloc = [&](size_t elems) { void* p = wsb + off; off += ((elems * 4 + 255) & ~(size_t)255); return p; };
    int*      bcnt       = (int*)alloc(NBUCK);
    int*      bbase      = (int*)alloc(NBUCK + 1);
    int*      bcur       = (int*)alloc(NBUCK);
    int*      blkhist    = (int*)alloc((size_t)PART_BLOCKS * NBUCK);
    int*      row_start  = (int*)alloc(N_NODES);
    int*      degi       = (int*)alloc(N_NODES);
    float*    dinv       = (float*)alloc(N_NODES);
    unsigned* packed     = (unsigned*)alloc(N_NODES);
    float*    M          = (float*)alloc(VOCAB * H);
    int*      sorted_row = (int*)alloc(N_EDGES);
    unsigned* sorted_pk  = (unsigned*)alloc(N_EDGES);
    float*    h          = (float*)alloc((size_t)N_NODES * H);
    unsigned short* t    = (unsigned short*)alloc((size_t)N_NODES * H / 2);  // bf16

    // packed staging (int[N_EDGES] = 12.8 MB) aliases t (dead until k_linear layer 1)
    int* staging = (int*)t;

    const int B = 256;
    const int gNH = (N_NODES * H + B - 1) / B;
    const int gLin = ((N_NODES + LIN_NODES_PER_WAVE - 1) / LIN_NODES_PER_WAVE * 64 + B - 1) / B;
    const int gG0 = (N_NODES + G0_NODES_PER_WAVE * 4 - 1) / (G0_NODES_PER_WAVE * 4);  // 3125

    hipLaunchKernelGGL(k_init, dim3((N_NODES + B - 1) / B), dim3(B), 0, stream, bcnt, degi);
    hipLaunchKernelGGL(k_bhist, dim3(PART_BLOCKS), dim3(256), 0, stream, col, bcnt, blkhist);
    hipLaunchKernelGGL(k_bscan, dim3(1), dim3(1024), 0, stream, bcnt, bbase, bcur);
    hipLaunchKernelGGL(k_binA, dim3(PART_BLOCKS), dim3(1024), 0, stream,
                       row, col, blkhist, bcur, staging, degi);
    hipLaunchKernelGGL(k_nodeinit, dim3(NBUCK), dim3(BUCK_NODES), 0, stream,
                       degi, bbase, x, row_start, dinv, packed);
    hipLaunchKernelGGL(k_binB, dim3(NBUCK), dim3(256), 0, stream, staging, bbase,
                       row_start, packed, sorted_row, sorted_pk);

    // layer 0: vocabulary-factored, streaming
    hipLaunchKernelGGL(k_premix, dim3(VOCAB), dim3(H), 0, stream, emb, conv_w, M);
    hipLaunchKernelGGL(k_gather0, dim3(gG0), dim3(B), 0, stream,
                       sorted_pk, row_start, degi, packed, M, dinv, conv_b, h);

    // layers 1,2
    for (int layer = 1; layer < N_LAYERS; ++layer) {
        hipLaunchKernelGGL(k_linear, dim3(gLin), dim3(B), 0, stream,
                           h, conv_w + (size_t)layer * H * H, dinv, t);
        hipLaunchKernelGGL(k_gather, dim3(gNH), dim3(B), 0, stream,
                           sorted_row, row_start, degi, t, dinv,
                           conv_b + (size_t)layer * H, h);
    }

    hipLaunchKernelGGL(k_poolmlp, dim3(N_GRAPHS), dim3(64), 0, stream,
                       h, batch, w1, b1, w2, b2, w3, b3, out);

    (void)in_sizes; (void)n_in; (void)out_size; (void)ws_size;
}

// Round 12
// 490.791 us; speedup vs baseline: 1.2062x; 1.2062x over previous
//
#include <hip/hip_runtime.h>

#define N_NODES 100000
#define N_EDGES 3200000
#define N_GRAPHS 2048
#define VOCAB 92
#define H 64
#define N_LAYERS 3

#define BUCK_BITS 7
#define BUCK_NODES (1 << BUCK_BITS)                          // 128 nodes / bucket
#define NBUCK ((N_NODES + BUCK_NODES - 1) / BUCK_NODES)      // 782

#define PART_BLOCKS 256
#define EDGES_PER_PART (N_EDGES / PART_BLOCKS)               // 12500

#define LIN_NODES_PER_WAVE 32
#define G0_NODES_PER_WAVE 8

// fp32 -> bf16 (round-to-nearest-even)
__device__ inline unsigned short f2bf(float f) {
    union { float f; unsigned u; } v; v.f = f;
    unsigned u = v.u;
    u += 0x7fffu + ((u >> 16) & 1u);
    return (unsigned short)(u >> 16);
}
__device__ inline float bfhi(unsigned p) {
    union { unsigned u; float f; } v; v.u = p & 0xffff0000u; return v.f;
}
__device__ inline float bflo(unsigned p) {
    union { unsigned u; float f; } v; v.u = p << 16; return v.f;
}

// ---------------- kernels ----------------

__global__ void k_init(int* bcnt) {
    int i = blockIdx.x * blockDim.x + threadIdx.x;
    if (i < NBUCK) bcnt[i] = 0;
}

// bucket histogram; also store per-block rows for binA reuse
__global__ void k_bhist(const int* __restrict__ col, int* __restrict__ bcnt,
                        int* __restrict__ blkhist) {
    __shared__ int lh[NBUCK];
    int tid = threadIdx.x;
    for (int i = tid; i < NBUCK; i += 256) lh[i] = 0;
    __syncthreads();
    int base = blockIdx.x * EDGES_PER_PART;
    for (int k = tid; k < EDGES_PER_PART; k += 256)
        atomicAdd(&lh[col[base + k] >> BUCK_BITS], 1);
    __syncthreads();
    int* myhist = blkhist + (size_t)blockIdx.x * NBUCK;
    for (int i = tid; i < NBUCK; i += 256) {
        int c = lh[i];
        myhist[i] = c;
        if (c) atomicAdd(&bcnt[i], c);
    }
}

// scan the 782 bucket counts; init reservation cursors
__global__ void k_bscan(const int* __restrict__ bcnt, int* __restrict__ bbase,
                        int* __restrict__ bcur) {
    __shared__ int s[1024];
    int tid = threadIdx.x;
    int v = (tid < NBUCK) ? bcnt[tid] : 0;
    s[tid] = v;
    __syncthreads();
    for (int off = 1; off < 1024; off <<= 1) {
        int x = (tid >= off) ? s[tid - off] : 0;
        __syncthreads();
        s[tid] += x;
        __syncthreads();
    }
    if (tid < NBUCK) {
        int e = s[tid] - v;
        bbase[tid] = e;
        bcur[tid] = e;
    }
    if (tid == 0) bbase[NBUCK] = N_EDGES;
}

// pass A: slice reservation from precomputed block hist, then rank + packed write
// (NO global degree atomics — r11's cross-XCD ping-pong lesson)
__global__ __launch_bounds__(1024) void k_binA(const int* __restrict__ row,
                                               const int* __restrict__ col,
                                               const int* __restrict__ blkhist,
                                               int* __restrict__ bcur,
                                               int* __restrict__ staging) {
    __shared__ int lcnt[NBUCK];
    __shared__ int lbase[NBUCK];
    int tid = threadIdx.x;
    int base = blockIdx.x * EDGES_PER_PART;
    const int* myhist = blkhist + (size_t)blockIdx.x * NBUCK;
    for (int i = tid; i < NBUCK; i += 1024) {
        int c = myhist[i];
        lbase[i] = c ? atomicAdd(&bcur[i], c) : 0;
        lcnt[i] = 0;
    }
    __syncthreads();
    for (int k = tid; k < EDGES_PER_PART; k += 1024) {
        int c = col[base + k];
        int b = c >> BUCK_BITS;
        int r = atomicAdd(&lcnt[b], 1);
        staging[lbase[b] + r] = row[base + k] | ((c & (BUCK_NODES - 1)) << 17);
    }
}

// pass B1: per-bucket degree histogram (LDS only) + scan ->
// degi / row_start / dinv / packed(x, dinv_bf16)
__global__ void k_binB1(const int* __restrict__ staging, const int* __restrict__ bbase,
                        const int* __restrict__ x, int* __restrict__ degi,
                        int* __restrict__ row_start, float* __restrict__ dinv,
                        unsigned* __restrict__ packed) {
    __shared__ int lde[BUCK_NODES];
    __shared__ int lsc[BUCK_NODES];
    int b = blockIdx.x, tid = threadIdx.x;
    int n0 = b << BUCK_BITS;
    int s0 = bbase[b], s1 = bbase[b + 1];
    if (tid < BUCK_NODES) lde[tid] = 0;
    __syncthreads();
    for (int i = s0 + tid; i < s1; i += 256)
        atomicAdd(&lde[staging[i] >> 17], 1);
    __syncthreads();
    if (tid < BUCK_NODES) lsc[tid] = lde[tid];
    __syncthreads();
    for (int off = 1; off < BUCK_NODES; off <<= 1) {
        int v = (tid >= off && tid < BUCK_NODES) ? lsc[tid - off] : 0;
        __syncthreads();
        if (tid < BUCK_NODES) lsc[tid] += v;
        __syncthreads();
    }
    if (tid < BUCK_NODES) {
        int n = n0 + tid;
        if (n < N_NODES) {
            int d = lde[tid];
            row_start[n] = s0 + lsc[tid] - d;
            degi[n] = d;
            float dv = rsqrtf((float)(d + 1));
            dinv[n] = dv;
            packed[n] = ((unsigned)f2bf(dv) << 16) | (unsigned)x[n];
        }
    }
}

// pass B2: scatter; also materializes the packed stream in edge order
// (packed[] is complete — binB1 ran for all buckets)
__global__ void k_binB2(const int* __restrict__ staging, const int* __restrict__ bbase,
                        const int* __restrict__ row_start, const unsigned* __restrict__ packed,
                        int* __restrict__ sorted_row, unsigned* __restrict__ sorted_pk) {
    __shared__ int lde[BUCK_NODES];
    __shared__ int lrs[BUCK_NODES];
    int b = blockIdx.x, tid = threadIdx.x;
    int n0 = b << BUCK_BITS;
    int s0 = bbase[b], s1 = bbase[b + 1];
    if (tid < BUCK_NODES) {
        lde[tid] = 0;
        int n = n0 + tid;
        lrs[tid] = (n < N_NODES) ? row_start[n] : 0;
    }
    __syncthreads();
    for (int i = s0 + tid; i < s1; i += 256) {
        int p = staging[i];
        int ln = p >> 17;
        int r = atomicAdd(&lde[ln], 1);
        int rw = p & 0x1FFFF;
        int pos = lrs[ln] + r;
        sorted_row[pos] = rw;
        sorted_pk[pos] = packed[rw];
    }
}

// M = emb @ W0 (92 x 64, f32). One block (64 threads) per vocab row.
__global__ void k_premix(const float* __restrict__ emb, const float* __restrict__ W0,
                         float* __restrict__ M) {
    int v = blockIdx.x, c = threadIdx.x;
    float acc = 0.0f;
#pragma unroll
    for (int k = 0; k < H; ++k) acc += emb[v * H + k] * W0[k * H + c];
    M[v * H + c] = acc;
}

// layer-0 gather: acc[n] = sum_e dinv_bf16[r] * M[x[r]], reading the sequential
// sorted_pk stream (no dependent loads). M staged in LDS as bf16x2 (11.75 KB).
__global__ __launch_bounds__(256) void k_gather0(const unsigned* __restrict__ sorted_pk,
                                                 const int* __restrict__ row_start,
                                                 const int* __restrict__ degi,
                                                 const unsigned* __restrict__ packed,
                                                 const float* __restrict__ M,
                                                 const float* __restrict__ dinv,
                                                 const float* __restrict__ bias,
                                                 float* __restrict__ h) {
    __shared__ unsigned Mb[VOCAB * 32];  // bf16x2 per (row, channel-pair)
    int tid = threadIdx.x;
    const float2* Mg = (const float2*)M;
    for (int i = tid; i < VOCAB * 32; i += 256) {
        float2 m = Mg[i];
        Mb[i] = ((unsigned)f2bf(m.y) << 16) | (unsigned)f2bf(m.x);
    }
    __syncthreads();
    int lane = tid & 63;
    int half = lane >> 5;
    int sub = lane & 31;
    int wid = (blockIdx.x * blockDim.x + tid) >> 6;
    int nbase = wid * G0_NODES_PER_WAVE;
    const float2* b2 = (const float2*)bias;
    float2 bb = b2[sub];
    float2* h2 = (float2*)h;
    for (int ni = 0; ni < G0_NODES_PER_WAVE; ++ni) {
        int n = nbase + ni;
        if (n >= N_NODES) break;
        int start = row_start[n];
        int d = degi[n];
        float ax = 0.0f, ay = 0.0f;
        int e = half;
        for (; e + 14 < d; e += 16) {
            unsigned p[8];
#pragma unroll
            for (int j = 0; j < 8; ++j) p[j] = sorted_pk[start + e + 2 * j];
#pragma unroll
            for (int j = 0; j < 8; ++j) {
                float dv = __uint_as_float(p[j] & 0xffff0000u);
                unsigned m = Mb[(p[j] & 127u) * 32 + sub];
                ax += dv * bflo(m); ay += dv * bfhi(m);
            }
        }
        for (; e + 6 < d; e += 8) {
            unsigned p[4];
#pragma unroll
            for (int j = 0; j < 4; ++j) p[j] = sorted_pk[start + e + 2 * j];
#pragma unroll
            for (int j = 0; j < 4; ++j) {
                float dv = __uint_as_float(p[j] & 0xffff0000u);
                unsigned m = Mb[(p[j] & 127u) * 32 + sub];
                ax += dv * bflo(m); ay += dv * bfhi(m);
            }
        }
        for (; e < d; e += 2) {
            unsigned p = sorted_pk[start + e];
            float dv = __uint_as_float(p & 0xffff0000u);
            unsigned m = Mb[(p & 127u) * 32 + sub];
            ax += dv * bflo(m); ay += dv * bfhi(m);
        }
        ax += __shfl_xor(ax, 32, 64);
        ay += __shfl_xor(ay, 32, 64);
        if (half == 0) {
            unsigned ps = packed[n];  // self-loop term
            float dvs = __uint_as_float(ps & 0xffff0000u);
            unsigned ms = Mb[(ps & 127u) * 32 + sub];
            ax += dvs * bflo(ms); ay += dvs * bfhi(ms);
            float di = dinv[n];
            h2[(size_t)n * 32 + sub] = make_float2(fmaxf(ax * di + bb.x, 0.0f),
                                                   fmaxf(ay * di + bb.y, 0.0f));
        }
    }
}

// t' = bf16( dinv[n] * (h @ W) )  (layers 1,2)
__global__ __launch_bounds__(256) void k_linear(const float* __restrict__ hin,
                                                const float* __restrict__ W,
                                                const float* __restrict__ dinv,
                                                unsigned short* __restrict__ t) {
    int lane = threadIdx.x & 63;
    int wid = (blockIdx.x * blockDim.x + threadIdx.x) >> 6;
    float wreg[H];
#pragma unroll
    for (int k = 0; k < H; ++k) wreg[k] = W[k * H + lane];
    int n0 = wid * LIN_NODES_PER_WAVE;
    if (n0 >= N_NODES) return;
    for (int i = 0; i < LIN_NODES_PER_WAVE; ++i) {
        int n = __builtin_amdgcn_readfirstlane(n0 + i);
        if (n >= N_NODES) break;
        const float* hr = hin + (size_t)n * H;
        float acc = 0.0f;
#pragma unroll
        for (int k = 0; k < H; ++k) acc += hr[k] * wreg[k];
        t[(size_t)n * H + lane] = f2bf(acc * dinv[n]);
    }
}

// layers 1-2 gather + finalize: one wave per node; 2 half-waves, bf16x2 channels
__global__ void k_gather(const int* __restrict__ sorted_row, const int* __restrict__ row_start,
                         const int* __restrict__ degi, const unsigned short* __restrict__ t,
                         const float* __restrict__ dinv, const float* __restrict__ bias,
                         float* __restrict__ h) {
    int gid = blockIdx.x * blockDim.x + threadIdx.x;
    int n = gid >> 6;
    if (n >= N_NODES) return;
    int lane = threadIdx.x & 63;
    int half = lane >> 5;
    int sub = lane & 31;
    const unsigned* t2 = (const unsigned*)t;
    int start = row_start[n];
    int d = degi[n];
    float ax = 0.0f, ay = 0.0f;
    int e = half;
    for (; e + 14 < d; e += 16) {
        unsigned p[8];
#pragma unroll
        for (int j = 0; j < 8; ++j)
            p[j] = t2[(size_t)sorted_row[start + e + 2 * j] * 32 + sub];
#pragma unroll
        for (int j = 0; j < 8; ++j) { ax += bflo(p[j]); ay += bfhi(p[j]); }
    }
    for (; e + 6 < d; e += 8) {
        unsigned p[4];
#pragma unroll
        for (int j = 0; j < 4; ++j)
            p[j] = t2[(size_t)sorted_row[start + e + 2 * j] * 32 + sub];
#pragma unroll
        for (int j = 0; j < 4; ++j) { ax += bflo(p[j]); ay += bfhi(p[j]); }
    }
    for (; e < d; e += 2) {
        unsigned p = t2[(size_t)sorted_row[start + e] * 32 + sub];
        ax += bflo(p); ay += bfhi(p);
    }
    ax += __shfl_xor(ax, 32, 64);
    ay += __shfl_xor(ay, 32, 64);
    if (half == 0) {
        unsigned self = t2[(size_t)n * 32 + sub];
        ax += bflo(self); ay += bfhi(self);
        float di = dinv[n];
        const float2* b2 = (const float2*)bias;
        float2 bb = b2[sub];
        float2* h2 = (float2*)h;
        float2 hp = h2[(size_t)n * 32 + sub];  // residual (layers 1,2 only)
        float vx = hp.x + fmaxf(ax * di + bb.x, 0.0f);
        float vy = hp.y + fmaxf(ay * di + bb.y, 0.0f);
        h2[(size_t)n * 32 + sub] = make_float2(vx, vy);
    }
}

// fused mean-pool + MLP: one wave per graph (batch sorted -> binary search)
__global__ void k_poolmlp(const float* __restrict__ h, const int* __restrict__ batch,
                          const float* __restrict__ w1, const float* __restrict__ b1,
                          const float* __restrict__ w2, const float* __restrict__ b2,
                          const float* __restrict__ w3, const float* __restrict__ b3,
                          float* __restrict__ out) {
    __shared__ float sg[H];
    __shared__ float s1[32];
    __shared__ float s2[16];
    int g = blockIdx.x, tid = threadIdx.x;
    int lo = 0, hi = N_NODES;
    while (lo < hi) { int mid = (lo + hi) >> 1; if (batch[mid] < g) lo = mid + 1; else hi = mid; }
    int lo2 = lo, hi2 = N_NODES;
    while (lo2 < hi2) { int mid = (lo2 + hi2) >> 1; if (batch[mid] < g + 1) lo2 = mid + 1; else hi2 = mid; }
    float acc = 0.0f;
    for (int n = lo; n < lo2; ++n) acc += h[(size_t)n * H + tid];
    float cntf = (float)(lo2 - lo);
    sg[tid] = acc / fmaxf(cntf, 1.0f);
    __syncthreads();
    if (tid < 32) {
        float a = b1[tid];
#pragma unroll
        for (int k = 0; k < H; ++k) a += sg[k] * w1[k * 32 + tid];
        s1[tid] = fmaxf(a, 0.0f);
    }
    __syncthreads();
    if (tid < 16) {
        float a = b2[tid];
#pragma unroll
        for (int k = 0; k < 32; ++k) a += s1[k] * w2[k * 16 + tid];
        s2[tid] = fmaxf(a, 0.0f);
    }
    __syncthreads();
    if (tid == 0) {
        float a = b3[0];
#pragma unroll
        for (int k = 0; k < 16; ++k) a += s2[k] * w3[k];
        out[g] = a;
    }
}

// ---------------- launch ----------------

extern "C" void kernel_launch(void* const* d_in, const int* in_sizes, int n_in,
                              void* d_out, int out_size, void* d_ws, size_t ws_size,
                              hipStream_t stream) {
    const int*   x      = (const int*)d_in[0];
    const int*   eidx   = (const int*)d_in[1];   // (2, E): row = eidx, col = eidx + E
    const int*   batch  = (const int*)d_in[2];
    const float* emb    = (const float*)d_in[3];
    const float* conv_w = (const float*)d_in[4];
    const float* conv_b = (const float*)d_in[5];
    const float* w1     = (const float*)d_in[6];
    const float* b1     = (const float*)d_in[7];
    const float* w2     = (const float*)d_in[8];
    const float* b2     = (const float*)d_in[9];
    const float* w3     = (const float*)d_in[10];
    const float* b3     = (const float*)d_in[11];
    float* out = (float*)d_out;

    const int* row = eidx;
    const int* col = eidx + N_EDGES;

    // workspace layout (4-byte units)
    char* wsb = (char*)d_ws;
    size_t off = 0;
    auto alloc = [&](size_t elems) { void* p = wsb + off; off += ((elems * 4 + 255) & ~(size_t)255); return p; };
    int*      bcnt       = (int*)alloc(NBUCK);
    int*      bbase      = (int*)alloc(NBUCK + 1);
    int*      bcur       = (int*)alloc(NBUCK);
    int*      blkhist    = (int*)alloc((size_t)PART_BLOCKS * NBUCK);
    int*      row_start  = (int*)alloc(N_NODES);
    int*      degi       = (int*)alloc(N_NODES);
    float*    dinv       = (float*)alloc(N_NODES);
    unsigned* packed     = (unsigned*)alloc(N_NODES);
    float*    M          = (float*)alloc(VOCAB * H);
    int*      sorted_row = (int*)alloc(N_EDGES);
    unsigned* sorted_pk  = (unsigned*)alloc(N_EDGES);
    float*    h          = (float*)alloc((size_t)N_NODES * H);
    unsigned short* t    = (unsigned short*)alloc((size_t)N_NODES * H / 2);  // bf16

    // packed staging (int[N_EDGES] = 12.8 MB) aliases t (dead until k_linear layer 1)
    int* staging = (int*)t;

    const int B = 256;
    const int gNH = (N_NODES * H + B - 1) / B;
    const int gLin = ((N_NODES + LIN_NODES_PER_WAVE - 1) / LIN_NODES_PER_WAVE * 64 + B - 1) / B;
    const int gG0 = (N_NODES + G0_NODES_PER_WAVE * 4 - 1) / (G0_NODES_PER_WAVE * 4);  // 3125

    hipLaunchKernelGGL(k_init, dim3((NBUCK + B - 1) / B), dim3(B), 0, stream, bcnt);
    hipLaunchKernelGGL(k_bhist, dim3(PART_BLOCKS), dim3(256), 0, stream, col, bcnt, blkhist);
    hipLaunchKernelGGL(k_bscan, dim3(1), dim3(1024), 0, stream, bcnt, bbase, bcur);
    hipLaunchKernelGGL(k_binA, dim3(PART_BLOCKS), dim3(1024), 0, stream,
                       row, col, blkhist, bcur, staging);
    hipLaunchKernelGGL(k_binB1, dim3(NBUCK), dim3(256), 0, stream, staging, bbase, x,
                       degi, row_start, dinv, packed);
    hipLaunchKernelGGL(k_binB2, dim3(NBUCK), dim3(256), 0, stream, staging, bbase,
                       row_start, packed, sorted_row, sorted_pk);

    // layer 0: vocabulary-factored, streaming
    hipLaunchKernelGGL(k_premix, dim3(VOCAB), dim3(H), 0, stream, emb, conv_w, M);
    hipLaunchKernelGGL(k_gather0, dim3(gG0), dim3(B), 0, stream,
                       sorted_pk, row_start, degi, packed, M, dinv, conv_b, h);

    // layers 1,2
    for (int layer = 1; layer < N_LAYERS; ++layer) {
        hipLaunchKernelGGL(k_linear, dim3(gLin), dim3(B), 0, stream,
                           h, conv_w + (size_t)layer * H * H, dinv, t);
        hipLaunchKernelGGL(k_gather, dim3(gNH), dim3(B), 0, stream,
                           sorted_row, row_start, degi, t, dinv,
                           conv_b + (size_t)layer * H, h);
    }

    hipLaunchKernelGGL(k_poolmlp, dim3(N_GRAPHS), dim3(64), 0, stream,
                       h, batch, w1, b1, w2, b2, w3, b3, out);

    (void)in_sizes; (void)n_in; (void)out_size; (void)ws_size;
}

// Round 13
// 470.332 us; speedup vs baseline: 1.2587x; 1.0435x over previous
//
#include <hip/hip_runtime.h>

#define N_NODES 100000
#define N_EDGES 3200000
#define N_GRAPHS 2048
#define VOCAB 92
#define H 64
#define N_LAYERS 3

#define BUCK_BITS 7
#define BUCK_NODES (1 << BUCK_BITS)                          // 128 nodes / bucket
#define NBUCK ((N_NODES + BUCK_NODES - 1) / BUCK_NODES)      // 782

#define PART_BLOCKS 512
#define PART_THREADS 512
#define EDGES_PER_PART (N_EDGES / PART_BLOCKS)               // 6250

#define LIN_NODES_PER_WAVE 32
#define G0_NODES_PER_WAVE 8

// fp32 -> bf16 (round-to-nearest-even)
__device__ inline unsigned short f2bf(float f) {
    union { float f; unsigned u; } v; v.f = f;
    unsigned u = v.u;
    u += 0x7fffu + ((u >> 16) & 1u);
    return (unsigned short)(u >> 16);
}
__device__ inline float bfhi(unsigned p) {
    union { unsigned u; float f; } v; v.u = p & 0xffff0000u; return v.f;
}
__device__ inline float bflo(unsigned p) {
    union { unsigned u; float f; } v; v.u = p << 16; return v.f;
}

// ---------------- kernels ----------------

__global__ void k_init(int* bcnt) {
    int i = blockIdx.x * blockDim.x + threadIdx.x;
    if (i < NBUCK) bcnt[i] = 0;
}

// bucket histogram; also store per-block rows for binA reuse
__global__ __launch_bounds__(PART_THREADS) void k_bhist(const int* __restrict__ col,
                                                        int* __restrict__ bcnt,
                                                        int* __restrict__ blkhist) {
    __shared__ int lh[NBUCK];
    int tid = threadIdx.x;
    for (int i = tid; i < NBUCK; i += PART_THREADS) lh[i] = 0;
    __syncthreads();
    int base = blockIdx.x * EDGES_PER_PART;
    for (int k = tid; k < EDGES_PER_PART; k += PART_THREADS)
        atomicAdd(&lh[col[base + k] >> BUCK_BITS], 1);
    __syncthreads();
    int* myhist = blkhist + (size_t)blockIdx.x * NBUCK;
    for (int i = tid; i < NBUCK; i += PART_THREADS) {
        int c = lh[i];
        myhist[i] = c;
        if (c) atomicAdd(&bcnt[i], c);
    }
}

// scan the 782 bucket counts; init reservation cursors
__global__ void k_bscan(const int* __restrict__ bcnt, int* __restrict__ bbase,
                        int* __restrict__ bcur) {
    __shared__ int s[1024];
    int tid = threadIdx.x;
    int v = (tid < NBUCK) ? bcnt[tid] : 0;
    s[tid] = v;
    __syncthreads();
    for (int off = 1; off < 1024; off <<= 1) {
        int x = (tid >= off) ? s[tid - off] : 0;
        __syncthreads();
        s[tid] += x;
        __syncthreads();
    }
    if (tid < NBUCK) {
        int e = s[tid] - v;
        bbase[tid] = e;
        bcur[tid] = e;
    }
    if (tid == 0) bbase[NBUCK] = N_EDGES;
}

// pass A: slice reservation from precomputed block hist, then rank + packed write
__global__ __launch_bounds__(PART_THREADS) void k_binA(const int* __restrict__ row,
                                                       const int* __restrict__ col,
                                                       const int* __restrict__ blkhist,
                                                       int* __restrict__ bcur,
                                                       int* __restrict__ staging) {
    __shared__ int lcnt[NBUCK];
    __shared__ int lbase[NBUCK];
    int tid = threadIdx.x;
    int base = blockIdx.x * EDGES_PER_PART;
    const int* myhist = blkhist + (size_t)blockIdx.x * NBUCK;
    for (int i = tid; i < NBUCK; i += PART_THREADS) {
        int c = myhist[i];
        lbase[i] = c ? atomicAdd(&bcur[i], c) : 0;
        lcnt[i] = 0;
    }
    __syncthreads();
    for (int k = tid; k < EDGES_PER_PART; k += PART_THREADS) {
        int c = col[base + k];
        int b = c >> BUCK_BITS;
        int r = atomicAdd(&lcnt[b], 1);
        staging[lbase[b] + r] = row[base + k] | ((c & (BUCK_NODES - 1)) << 17);
    }
}

// pass B: per-bucket degree hist/scan -> degi/row_start/dinv + packed(x, dinv_bf16),
// then local sort (r10's proven fused version)
__global__ void k_binB(const int* __restrict__ staging, const int* __restrict__ bbase,
                       const int* __restrict__ x,
                       int* __restrict__ sorted_row, int* __restrict__ degi,
                       int* __restrict__ row_start, float* __restrict__ dinv,
                       unsigned* __restrict__ packed) {
    __shared__ int lde[BUCK_NODES];
    __shared__ int lsc[BUCK_NODES];
    int b = blockIdx.x, tid = threadIdx.x;
    int n0 = b << BUCK_BITS;
    int s0 = bbase[b], s1 = bbase[b + 1];
    if (tid < BUCK_NODES) lde[tid] = 0;
    __syncthreads();
    for (int i = s0 + tid; i < s1; i += 256)
        atomicAdd(&lde[staging[i] >> 17], 1);
    __syncthreads();
    if (tid < BUCK_NODES) lsc[tid] = lde[tid];
    __syncthreads();
    for (int off = 1; off < BUCK_NODES; off <<= 1) {
        int v = (tid >= off && tid < BUCK_NODES) ? lsc[tid - off] : 0;
        __syncthreads();
        if (tid < BUCK_NODES) lsc[tid] += v;
        __syncthreads();
    }
    if (tid < BUCK_NODES) {
        int n = n0 + tid;
        int excl = lsc[tid] - lde[tid];
        if (n < N_NODES) {
            row_start[n] = s0 + excl;
            degi[n] = lde[tid];
            float dv = rsqrtf((float)(lde[tid] + 1));
            dinv[n] = dv;
            packed[n] = ((unsigned)f2bf(dv) << 16) | (unsigned)x[n];
        }
        lsc[tid] = excl;
        lde[tid] = 0;
    }
    __syncthreads();
    for (int i = s0 + tid; i < s1; i += 256) {
        int p = staging[i];
        int ln = p >> 17;
        int r = atomicAdd(&lde[ln], 1);
        sorted_row[s0 + lsc[ln] + r] = p & 0x1FFFF;
    }
}

// M = emb @ W0 (92 x 64, f32). One block (64 threads) per vocab row.
__global__ void k_premix(const float* __restrict__ emb, const float* __restrict__ W0,
                         float* __restrict__ M) {
    int v = blockIdx.x, c = threadIdx.x;
    float acc = 0.0f;
#pragma unroll
    for (int k = 0; k < H; ++k) acc += emb[v * H + k] * W0[k * H + c];
    M[v * H + c] = acc;
}

// layer-0 gather: acc[n] = sum_e dinv_bf16[r] * M[x[r]].
// M staged in LDS as bf16x2 (11.75 KB); 8 nodes/wave; 16-deep two-level pipeline
// (16 sorted_row loads, then 16 packed loads in flight).
__global__ __launch_bounds__(256) void k_gather0(const int* __restrict__ sorted_row,
                                                 const int* __restrict__ row_start,
                                                 const int* __restrict__ degi,
                                                 const unsigned* __restrict__ packed,
                                                 const float* __restrict__ M,
                                                 const float* __restrict__ dinv,
                                                 const float* __restrict__ bias,
                                                 float* __restrict__ h) {
    __shared__ unsigned Mb[VOCAB * 32];  // bf16x2 per (row, channel-pair)
    int tid = threadIdx.x;
    const float2* Mg = (const float2*)M;
    for (int i = tid; i < VOCAB * 32; i += 256) {
        float2 m = Mg[i];
        Mb[i] = ((unsigned)f2bf(m.y) << 16) | (unsigned)f2bf(m.x);
    }
    __syncthreads();
    int lane = tid & 63;
    int half = lane >> 5;
    int sub = lane & 31;
    int wid = (blockIdx.x * blockDim.x + tid) >> 6;
    int nbase = wid * G0_NODES_PER_WAVE;
    const float2* b2 = (const float2*)bias;
    float2 bb = b2[sub];
    float2* h2 = (float2*)h;
    for (int ni = 0; ni < G0_NODES_PER_WAVE; ++ni) {
        int n = nbase + ni;
        if (n >= N_NODES) break;
        int start = row_start[n];
        int d = degi[n];
        float ax = 0.0f, ay = 0.0f;
        int e = half;
        for (; e + 30 < d; e += 32) {
            int sr[16];
#pragma unroll
            for (int j = 0; j < 16; ++j) sr[j] = sorted_row[start + e + 2 * j];
            unsigned p[16];
#pragma unroll
            for (int j = 0; j < 16; ++j) p[j] = packed[sr[j]];
#pragma unroll
            for (int j = 0; j < 16; ++j) {
                float dv = __uint_as_float(p[j] & 0xffff0000u);
                unsigned m = Mb[(p[j] & 127u) * 32 + sub];
                ax += dv * bflo(m); ay += dv * bfhi(m);
            }
        }
        for (; e + 14 < d; e += 16) {
            int sr[8];
#pragma unroll
            for (int j = 0; j < 8; ++j) sr[j] = sorted_row[start + e + 2 * j];
            unsigned p[8];
#pragma unroll
            for (int j = 0; j < 8; ++j) p[j] = packed[sr[j]];
#pragma unroll
            for (int j = 0; j < 8; ++j) {
                float dv = __uint_as_float(p[j] & 0xffff0000u);
                unsigned m = Mb[(p[j] & 127u) * 32 + sub];
                ax += dv * bflo(m); ay += dv * bfhi(m);
            }
        }
        for (; e + 6 < d; e += 8) {
            unsigned p[4];
#pragma unroll
            for (int j = 0; j < 4; ++j)
                p[j] = packed[sorted_row[start + e + 2 * j]];
#pragma unroll
            for (int j = 0; j < 4; ++j) {
                float dv = __uint_as_float(p[j] & 0xffff0000u);
                unsigned m = Mb[(p[j] & 127u) * 32 + sub];
                ax += dv * bflo(m); ay += dv * bfhi(m);
            }
        }
        for (; e < d; e += 2) {
            unsigned p = packed[sorted_row[start + e]];
            float dv = __uint_as_float(p & 0xffff0000u);
            unsigned m = Mb[(p & 127u) * 32 + sub];
            ax += dv * bflo(m); ay += dv * bfhi(m);
        }
        ax += __shfl_xor(ax, 32, 64);
        ay += __shfl_xor(ay, 32, 64);
        if (half == 0) {
            unsigned ps = packed[n];  // self-loop term
            float dvs = __uint_as_float(ps & 0xffff0000u);
            unsigned ms = Mb[(ps & 127u) * 32 + sub];
            ax += dvs * bflo(ms); ay += dvs * bfhi(ms);
            float di = dinv[n];
            h2[(size_t)n * 32 + sub] = make_float2(fmaxf(ax * di + bb.x, 0.0f),
                                                   fmaxf(ay * di + bb.y, 0.0f));
        }
    }
}

// t' = bf16( dinv[n] * (h @ W) )  (layers 1,2)
__global__ __launch_bounds__(256) void k_linear(const float* __restrict__ hin,
                                                const float* __restrict__ W,
                                                const float* __restrict__ dinv,
                                                unsigned short* __restrict__ t) {
    int lane = threadIdx.x & 63;
    int wid = (blockIdx.x * blockDim.x + threadIdx.x) >> 6;
    float wreg[H];
#pragma unroll
    for (int k = 0; k < H; ++k) wreg[k] = W[k * H + lane];
    int n0 = wid * LIN_NODES_PER_WAVE;
    if (n0 >= N_NODES) return;
    for (int i = 0; i < LIN_NODES_PER_WAVE; ++i) {
        int n = __builtin_amdgcn_readfirstlane(n0 + i);
        if (n >= N_NODES) break;
        const float* hr = hin + (size_t)n * H;
        float acc = 0.0f;
#pragma unroll
        for (int k = 0; k < H; ++k) acc += hr[k] * wreg[k];
        t[(size_t)n * H + lane] = f2bf(acc * dinv[n]);
    }
}

// layers 1-2 gather + finalize: one wave per node; 2 half-waves, bf16x2 channels
__global__ void k_gather(const int* __restrict__ sorted_row, const int* __restrict__ row_start,
                         const int* __restrict__ degi, const unsigned short* __restrict__ t,
                         const float* __restrict__ dinv, const float* __restrict__ bias,
                         float* __restrict__ h) {
    int gid = blockIdx.x * blockDim.x + threadIdx.x;
    int n = gid >> 6;
    if (n >= N_NODES) return;
    int lane = threadIdx.x & 63;
    int half = lane >> 5;
    int sub = lane & 31;
    const unsigned* t2 = (const unsigned*)t;
    int start = row_start[n];
    int d = degi[n];
    float ax = 0.0f, ay = 0.0f;
    int e = half;
    for (; e + 14 < d; e += 16) {
        unsigned p[8];
#pragma unroll
        for (int j = 0; j < 8; ++j)
            p[j] = t2[(size_t)sorted_row[start + e + 2 * j] * 32 + sub];
#pragma unroll
        for (int j = 0; j < 8; ++j) { ax += bflo(p[j]); ay += bfhi(p[j]); }
    }
    for (; e + 6 < d; e += 8) {
        unsigned p[4];
#pragma unroll
        for (int j = 0; j < 4; ++j)
            p[j] = t2[(size_t)sorted_row[start + e + 2 * j] * 32 + sub];
#pragma unroll
        for (int j = 0; j < 4; ++j) { ax += bflo(p[j]); ay += bfhi(p[j]); }
    }
    for (; e < d; e += 2) {
        unsigned p = t2[(size_t)sorted_row[start + e] * 32 + sub];
        ax += bflo(p); ay += bfhi(p);
    }
    ax += __shfl_xor(ax, 32, 64);
    ay += __shfl_xor(ay, 32, 64);
    if (half == 0) {
        unsigned self = t2[(size_t)n * 32 + sub];
        ax += bflo(self); ay += bfhi(self);
        float di = dinv[n];
        const float2* b2 = (const float2*)bias;
        float2 bb = b2[sub];
        float2* h2 = (float2*)h;
        float2 hp = h2[(size_t)n * 32 + sub];  // residual (layers 1,2 only)
        float vx = hp.x + fmaxf(ax * di + bb.x, 0.0f);
        float vy = hp.y + fmaxf(ay * di + bb.y, 0.0f);
        h2[(size_t)n * 32 + sub] = make_float2(vx, vy);
    }
}

// fused mean-pool + MLP: one wave per graph (batch sorted -> binary search)
__global__ void k_poolmlp(const float* __restrict__ h, const int* __restrict__ batch,
                          const float* __restrict__ w1, const float* __restrict__ b1,
                          const float* __restrict__ w2, const float* __restrict__ b2,
                          const float* __restrict__ w3, const float* __restrict__ b3,
                          float* __restrict__ out) {
    __shared__ float sg[H];
    __shared__ float s1[32];
    __shared__ float s2[16];
    int g = blockIdx.x, tid = threadIdx.x;
    int lo = 0, hi = N_NODES;
    while (lo < hi) { int mid = (lo + hi) >> 1; if (batch[mid] < g) lo = mid + 1; else hi = mid; }
    int lo2 = lo, hi2 = N_NODES;
    while (lo2 < hi2) { int mid = (lo2 + hi2) >> 1; if (batch[mid] < g + 1) lo2 = mid + 1; else hi2 = mid; }
    float acc = 0.0f;
    for (int n = lo; n < lo2; ++n) acc += h[(size_t)n * H + tid];
    float cntf = (float)(lo2 - lo);
    sg[tid] = acc / fmaxf(cntf, 1.0f);
    __syncthreads();
    if (tid < 32) {
        float a = b1[tid];
#pragma unroll
        for (int k = 0; k < H; ++k) a += sg[k] * w1[k * 32 + tid];
        s1[tid] = fmaxf(a, 0.0f);
    }
    __syncthreads();
    if (tid < 16) {
        float a = b2[tid];
#pragma unroll
        for (int k = 0; k < 32; ++k) a += s1[k] * w2[k * 16 + tid];
        s2[tid] = fmaxf(a, 0.0f);
    }
    __syncthreads();
    if (tid == 0) {
        float a = b3[0];
#pragma unroll
        for (int k = 0; k < 16; ++k) a += s2[k] * w3[k];
        out[g] = a;
    }
}

// ---------------- launch ----------------

extern "C" void kernel_launch(void* const* d_in, const int* in_sizes, int n_in,
                              void* d_out, int out_size, void* d_ws, size_t ws_size,
                              hipStream_t stream) {
    const int*   x      = (const int*)d_in[0];
    const int*   eidx   = (const int*)d_in[1];   // (2, E): row = eidx, col = eidx + E
    const int*   batch  = (const int*)d_in[2];
    const float* emb    = (const float*)d_in[3];
    const float* conv_w = (const float*)d_in[4];
    const float* conv_b = (const float*)d_in[5];
    const float* w1     = (const float*)d_in[6];
    const float* b1     = (const float*)d_in[7];
    const float* w2     = (const float*)d_in[8];
    const float* b2     = (const float*)d_in[9];
    const float* w3     = (const float*)d_in[10];
    const float* b3     = (const float*)d_in[11];
    float* out = (float*)d_out;

    const int* row = eidx;
    const int* col = eidx + N_EDGES;

    // workspace layout (4-byte units)
    char* wsb = (char*)d_ws;
    size_t off = 0;
    auto alloc = [&](size_t elems) { void* p = wsb + off; off += ((elems * 4 + 255) & ~(size_t)255); return p; };
    int*      bcnt       = (int*)alloc(NBUCK);
    int*      bbase      = (int*)alloc(NBUCK + 1);
    int*      bcur       = (int*)alloc(NBUCK);
    int*      blkhist    = (int*)alloc((size_t)PART_BLOCKS * NBUCK);
    int*      row_start  = (int*)alloc(N_NODES);
    int*      degi       = (int*)alloc(N_NODES);
    float*    dinv       = (float*)alloc(N_NODES);
    unsigned* packed     = (unsigned*)alloc(N_NODES);
    float*    M          = (float*)alloc(VOCAB * H);
    int*      sorted_row = (int*)alloc(N_EDGES);
    float*    h          = (float*)alloc((size_t)N_NODES * H);
    unsigned short* t    = (unsigned short*)alloc((size_t)N_NODES * H / 2);  // bf16

    // packed staging (int[N_EDGES] = 12.8 MB) aliases t (dead until k_linear layer 1)
    int* staging = (int*)t;

    const int B = 256;
    const int gNH = (N_NODES * H + B - 1) / B;
    const int gLin = ((N_NODES + LIN_NODES_PER_WAVE - 1) / LIN_NODES_PER_WAVE * 64 + B - 1) / B;
    const int gG0 = (N_NODES + G0_NODES_PER_WAVE * 4 - 1) / (G0_NODES_PER_WAVE * 4);  // 3125

    hipLaunchKernelGGL(k_init, dim3((NBUCK + B - 1) / B), dim3(B), 0, stream, bcnt);
    hipLaunchKernelGGL(k_bhist, dim3(PART_BLOCKS), dim3(PART_THREADS), 0, stream,
                       col, bcnt, blkhist);
    hipLaunchKernelGGL(k_bscan, dim3(1), dim3(1024), 0, stream, bcnt, bbase, bcur);
    hipLaunchKernelGGL(k_binA, dim3(PART_BLOCKS), dim3(PART_THREADS), 0, stream,
                       row, col, blkhist, bcur, staging);
    hipLaunchKernelGGL(k_binB, dim3(NBUCK), dim3(256), 0, stream, staging, bbase, x,
                       sorted_row, degi, row_start, dinv, packed);

    // layer 0: vocabulary-factored
    hipLaunchKernelGGL(k_premix, dim3(VOCAB), dim3(H), 0, stream, emb, conv_w, M);
    hipLaunchKernelGGL(k_gather0, dim3(gG0), dim3(B), 0, stream,
                       sorted_row, row_start, degi, packed, M, dinv, conv_b, h);

    // layers 1,2
    for (int layer = 1; layer < N_LAYERS; ++layer) {
        hipLaunchKernelGGL(k_linear, dim3(gLin), dim3(B), 0, stream,
                           h, conv_w + (size_t)layer * H * H, dinv, t);
        hipLaunchKernelGGL(k_gather, dim3(gNH), dim3(B), 0, stream,
                           sorted_row, row_start, degi, t, dinv,
                           conv_b + (size_t)layer * H, h);
    }

    hipLaunchKernelGGL(k_poolmlp, dim3(N_GRAPHS), dim3(64), 0, stream,
                       h, batch, w1, b1, w2, b2, w3, b3, out);

    (void)in_sizes; (void)n_in; (void)out_size; (void)ws_size;
}

// Round 14
// 458.314 us; speedup vs baseline: 1.2917x; 1.0262x over previous
//
#include <hip/hip_runtime.h>

#define N_NODES 100000
#define N_EDGES 3200000
#define N_GRAPHS 2048
#define VOCAB 92
#define H 64
#define N_LAYERS 3

#define BUCK_BITS 7
#define BUCK_NODES (1 << BUCK_BITS)                          // 128 nodes / bucket
#define NBUCK ((N_NODES + BUCK_NODES - 1) / BUCK_NODES)      // 782

#define PART_BLOCKS 256
#define EDGES_PER_PART (N_EDGES / PART_BLOCKS)               // 12500

#define LIN_NODES_PER_WAVE 32
#define G0_NODES_PER_WAVE 8

// fp32 -> bf16 (round-to-nearest-even)
__device__ inline unsigned short f2bf(float f) {
    union { float f; unsigned u; } v; v.f = f;
    unsigned u = v.u;
    u += 0x7fffu + ((u >> 16) & 1u);
    return (unsigned short)(u >> 16);
}
__device__ inline float bfhi(unsigned p) {
    union { unsigned u; float f; } v; v.u = p & 0xffff0000u; return v.f;
}
__device__ inline float bflo(unsigned p) {
    union { unsigned u; float f; } v; v.u = p << 16; return v.f;
}

// ---------------- kernels ----------------

__global__ void k_init(int* bcnt) {
    int i = blockIdx.x * blockDim.x + threadIdx.x;
    if (i < NBUCK) bcnt[i] = 0;
}

// bucket histogram; also store per-block rows for binA reuse
__global__ void k_bhist(const int* __restrict__ col, int* __restrict__ bcnt,
                        int* __restrict__ blkhist) {
    __shared__ int lh[NBUCK];
    int tid = threadIdx.x;
    for (int i = tid; i < NBUCK; i += 256) lh[i] = 0;
    __syncthreads();
    int base = blockIdx.x * EDGES_PER_PART;
    for (int k = tid; k < EDGES_PER_PART; k += 256)
        atomicAdd(&lh[col[base + k] >> BUCK_BITS], 1);
    __syncthreads();
    int* myhist = blkhist + (size_t)blockIdx.x * NBUCK;
    for (int i = tid; i < NBUCK; i += 256) {
        int c = lh[i];
        myhist[i] = c;
        if (c) atomicAdd(&bcnt[i], c);
    }
}

// scan the 782 bucket counts; init reservation cursors
__global__ void k_bscan(const int* __restrict__ bcnt, int* __restrict__ bbase,
                        int* __restrict__ bcur) {
    __shared__ int s[1024];
    int tid = threadIdx.x;
    int v = (tid < NBUCK) ? bcnt[tid] : 0;
    s[tid] = v;
    __syncthreads();
    for (int off = 1; off < 1024; off <<= 1) {
        int x = (tid >= off) ? s[tid - off] : 0;
        __syncthreads();
        s[tid] += x;
        __syncthreads();
    }
    if (tid < NBUCK) {
        int e = s[tid] - v;
        bbase[tid] = e;
        bcur[tid] = e;
    }
    if (tid == 0) bbase[NBUCK] = N_EDGES;
}

// pass A: slice reservation from precomputed block hist, then rank + packed write
__global__ __launch_bounds__(1024) void k_binA(const int* __restrict__ row,
                                               const int* __restrict__ col,
                                               const int* __restrict__ blkhist,
                                               int* __restrict__ bcur,
                                               int* __restrict__ staging) {
    __shared__ int lcnt[NBUCK];
    __shared__ int lbase[NBUCK];
    int tid = threadIdx.x;
    int base = blockIdx.x * EDGES_PER_PART;
    const int* myhist = blkhist + (size_t)blockIdx.x * NBUCK;
    for (int i = tid; i < NBUCK; i += 1024) {
        int c = myhist[i];
        lbase[i] = c ? atomicAdd(&bcur[i], c) : 0;
        lcnt[i] = 0;
    }
    __syncthreads();
    for (int k = tid; k < EDGES_PER_PART; k += 1024) {
        int c = col[base + k];
        int b = c >> BUCK_BITS;
        int r = atomicAdd(&lcnt[b], 1);
        staging[lbase[b] + r] = row[base + k] | ((c & (BUCK_NODES - 1)) << 17);
    }
}

// pass B: per-bucket degree hist/scan -> degi/row_start/dinv + packed(x, dinv_bf16),
// then local sort
__global__ void k_binB(const int* __restrict__ staging, const int* __restrict__ bbase,
                       const int* __restrict__ x,
                       int* __restrict__ sorted_row, int* __restrict__ degi,
                       int* __restrict__ row_start, float* __restrict__ dinv,
                       unsigned* __restrict__ packed) {
    __shared__ int lde[BUCK_NODES];
    __shared__ int lsc[BUCK_NODES];
    int b = blockIdx.x, tid = threadIdx.x;
    int n0 = b << BUCK_BITS;
    int s0 = bbase[b], s1 = bbase[b + 1];
    if (tid < BUCK_NODES) lde[tid] = 0;
    __syncthreads();
    for (int i = s0 + tid; i < s1; i += 256)
        atomicAdd(&lde[staging[i] >> 17], 1);
    __syncthreads();
    if (tid < BUCK_NODES) lsc[tid] = lde[tid];
    __syncthreads();
    for (int off = 1; off < BUCK_NODES; off <<= 1) {
        int v = (tid >= off && tid < BUCK_NODES) ? lsc[tid - off] : 0;
        __syncthreads();
        if (tid < BUCK_NODES) lsc[tid] += v;
        __syncthreads();
    }
    if (tid < BUCK_NODES) {
        int n = n0 + tid;
        int excl = lsc[tid] - lde[tid];
        if (n < N_NODES) {
            row_start[n] = s0 + excl;
            degi[n] = lde[tid];
            float dv = rsqrtf((float)(lde[tid] + 1));
            dinv[n] = dv;
            packed[n] = ((unsigned)f2bf(dv) << 16) | (unsigned)x[n];
        }
        lsc[tid] = excl;
        lde[tid] = 0;
    }
    __syncthreads();
    for (int i = s0 + tid; i < s1; i += 256) {
        int p = staging[i];
        int ln = p >> 17;
        int r = atomicAdd(&lde[ln], 1);
        sorted_row[s0 + lsc[ln] + r] = p & 0x1FFFF;
    }
}

// M = emb @ W0 (92 x 64, f32). One block (64 threads) per vocab row.
__global__ void k_premix(const float* __restrict__ emb, const float* __restrict__ W0,
                         float* __restrict__ M) {
    int v = blockIdx.x, c = threadIdx.x;
    float acc = 0.0f;
#pragma unroll
    for (int k = 0; k < H; ++k) acc += emb[v * H + k] * W0[k * H + c];
    M[v * H + c] = acc;
}

// layer-0 gather: acc[n] = sum_e dinv_bf16[r] * M[x[r]].
// M staged in LDS as bf16x2 (11.75 KB); 8 nodes/wave -> 3125 blocks for TLP.
__global__ __launch_bounds__(256) void k_gather0(const int* __restrict__ sorted_row,
                                                 const int* __restrict__ row_start,
                                                 const int* __restrict__ degi,
                                                 const unsigned* __restrict__ packed,
                                                 const float* __restrict__ M,
                                                 const float* __restrict__ dinv,
                                                 const float* __restrict__ bias,
                                                 float* __restrict__ h) {
    __shared__ unsigned Mb[VOCAB * 32];  // bf16x2 per (row, channel-pair)
    int tid = threadIdx.x;
    const float2* Mg = (const float2*)M;
    for (int i = tid; i < VOCAB * 32; i += 256) {
        float2 m = Mg[i];
        Mb[i] = ((unsigned)f2bf(m.y) << 16) | (unsigned)f2bf(m.x);
    }
    __syncthreads();
    int lane = tid & 63;
    int half = lane >> 5;
    int sub = lane & 31;
    int wid = (blockIdx.x * blockDim.x + tid) >> 6;
    int nbase = wid * G0_NODES_PER_WAVE;
    const float2* b2 = (const float2*)bias;
    float2 bb = b2[sub];
    float2* h2 = (float2*)h;
    for (int ni = 0; ni < G0_NODES_PER_WAVE; ++ni) {
        int n = nbase + ni;
        if (n >= N_NODES) break;
        int start = row_start[n];
        int d = degi[n];
        float ax = 0.0f, ay = 0.0f;
        int e = half;
        for (; e + 14 < d; e += 16) {
            unsigned p[8];
#pragma unroll
            for (int j = 0; j < 8; ++j)
                p[j] = packed[sorted_row[start + e + 2 * j]];
#pragma unroll
            for (int j = 0; j < 8; ++j) {
                float dv = __uint_as_float(p[j] & 0xffff0000u);
                unsigned m = Mb[(p[j] & 127u) * 32 + sub];
                ax += dv * bflo(m); ay += dv * bfhi(m);
            }
        }
        for (; e + 6 < d; e += 8) {
            unsigned p[4];
#pragma unroll
            for (int j = 0; j < 4; ++j)
                p[j] = packed[sorted_row[start + e + 2 * j]];
#pragma unroll
            for (int j = 0; j < 4; ++j) {
                float dv = __uint_as_float(p[j] & 0xffff0000u);
                unsigned m = Mb[(p[j] & 127u) * 32 + sub];
                ax += dv * bflo(m); ay += dv * bfhi(m);
            }
        }
        for (; e < d; e += 2) {
            unsigned p = packed[sorted_row[start + e]];
            float dv = __uint_as_float(p & 0xffff0000u);
            unsigned m = Mb[(p & 127u) * 32 + sub];
            ax += dv * bflo(m); ay += dv * bfhi(m);
        }
        ax += __shfl_xor(ax, 32, 64);
        ay += __shfl_xor(ay, 32, 64);
        if (half == 0) {
            unsigned ps = packed[n];  // self-loop term
            float dvs = __uint_as_float(ps & 0xffff0000u);
            unsigned ms = Mb[(ps & 127u) * 32 + sub];
            ax += dvs * bflo(ms); ay += dvs * bfhi(ms);
            float di = dinv[n];
            h2[(size_t)n * 32 + sub] = make_float2(fmaxf(ax * di + bb.x, 0.0f),
                                                   fmaxf(ay * di + bb.y, 0.0f));
        }
    }
}

// t' = bf16( dinv[n] * (h @ W) )  (layers 1,2)
__global__ __launch_bounds__(256) void k_linear(const float* __restrict__ hin,
                                                const float* __restrict__ W,
                                                const float* __restrict__ dinv,
                                                unsigned short* __restrict__ t) {
    int lane = threadIdx.x & 63;
    int wid = (blockIdx.x * blockDim.x + threadIdx.x) >> 6;
    float wreg[H];
#pragma unroll
    for (int k = 0; k < H; ++k) wreg[k] = W[k * H + lane];
    int n0 = wid * LIN_NODES_PER_WAVE;
    if (n0 >= N_NODES) return;
    for (int i = 0; i < LIN_NODES_PER_WAVE; ++i) {
        int n = __builtin_amdgcn_readfirstlane(n0 + i);
        if (n >= N_NODES) break;
        const float* hr = hin + (size_t)n * H;
        float acc = 0.0f;
#pragma unroll
        for (int k = 0; k < H; ++k) acc += hr[k] * wreg[k];
        t[(size_t)n * H + lane] = f2bf(acc * dinv[n]);
    }
}

// layers 1-2 gather + finalize: one wave per node; 2 half-waves, bf16x2 channels
__global__ void k_gather(const int* __restrict__ sorted_row, const int* __restrict__ row_start,
                         const int* __restrict__ degi, const unsigned short* __restrict__ t,
                         const float* __restrict__ dinv, const float* __restrict__ bias,
                         float* __restrict__ h) {
    int gid = blockIdx.x * blockDim.x + threadIdx.x;
    int n = gid >> 6;
    if (n >= N_NODES) return;
    int lane = threadIdx.x & 63;
    int half = lane >> 5;
    int sub = lane & 31;
    const unsigned* t2 = (const unsigned*)t;
    int start = row_start[n];
    int d = degi[n];
    float ax = 0.0f, ay = 0.0f;
    int e = half;
    for (; e + 14 < d; e += 16) {
        unsigned p[8];
#pragma unroll
        for (int j = 0; j < 8; ++j)
            p[j] = t2[(size_t)sorted_row[start + e + 2 * j] * 32 + sub];
#pragma unroll
        for (int j = 0; j < 8; ++j) { ax += bflo(p[j]); ay += bfhi(p[j]); }
    }
    for (; e + 6 < d; e += 8) {
        unsigned p[4];
#pragma unroll
        for (int j = 0; j < 4; ++j)
            p[j] = t2[(size_t)sorted_row[start + e + 2 * j] * 32 + sub];
#pragma unroll
        for (int j = 0; j < 4; ++j) { ax += bflo(p[j]); ay += bfhi(p[j]); }
    }
    for (; e < d; e += 2) {
        unsigned p = t2[(size_t)sorted_row[start + e] * 32 + sub];
        ax += bflo(p); ay += bfhi(p);
    }
    ax += __shfl_xor(ax, 32, 64);
    ay += __shfl_xor(ay, 32, 64);
    if (half == 0) {
        unsigned self = t2[(size_t)n * 32 + sub];
        ax += bflo(self); ay += bfhi(self);
        float di = dinv[n];
        const float2* b2 = (const float2*)bias;
        float2 bb = b2[sub];
        float2* h2 = (float2*)h;
        float2 hp = h2[(size_t)n * 32 + sub];  // residual (layers 1,2 only)
        float vx = hp.x + fmaxf(ax * di + bb.x, 0.0f);
        float vy = hp.y + fmaxf(ay * di + bb.y, 0.0f);
        h2[(size_t)n * 32 + sub] = make_float2(vx, vy);
    }
}

// fused mean-pool + MLP: one wave per graph (batch sorted -> binary search)
__global__ void k_poolmlp(const float* __restrict__ h, const int* __restrict__ batch,
                          const float* __restrict__ w1, const float* __restrict__ b1,
                          const float* __restrict__ w2, const float* __restrict__ b2,
                          const float* __restrict__ w3, const float* __restrict__ b3,
                          float* __restrict__ out) {
    __shared__ float sg[H];
    __shared__ float s1[32];
    __shared__ float s2[16];
    int g = blockIdx.x, tid = threadIdx.x;
    int lo = 0, hi = N_NODES;
    while (lo < hi) { int mid = (lo + hi) >> 1; if (batch[mid] < g) lo = mid + 1; else hi = mid; }
    int lo2 = lo, hi2 = N_NODES;
    while (lo2 < hi2) { int mid = (lo2 + hi2) >> 1; if (batch[mid] < g + 1) lo2 = mid + 1; else hi2 = mid; }
    float acc = 0.0f;
    for (int n = lo; n < lo2; ++n) acc += h[(size_t)n * H + tid];
    float cntf = (float)(lo2 - lo);
    sg[tid] = acc / fmaxf(cntf, 1.0f);
    __syncthreads();
    if (tid < 32) {
        float a = b1[tid];
#pragma unroll
        for (int k = 0; k < H; ++k) a += sg[k] * w1[k * 32 + tid];
        s1[tid] = fmaxf(a, 0.0f);
    }
    __syncthreads();
    if (tid < 16) {
        float a = b2[tid];
#pragma unroll
        for (int k = 0; k < 32; ++k) a += s1[k] * w2[k * 16 + tid];
        s2[tid] = fmaxf(a, 0.0f);
    }
    __syncthreads();
    if (tid == 0) {
        float a = b3[0];
#pragma unroll
        for (int k = 0; k < 16; ++k) a += s2[k] * w3[k];
        out[g] = a;
    }
}

// ---------------- launch ----------------

extern "C" void kernel_launch(void* const* d_in, const int* in_sizes, int n_in,
                              void* d_out, int out_size, void* d_ws, size_t ws_size,
                              hipStream_t stream) {
    const int*   x      = (const int*)d_in[0];
    const int*   eidx   = (const int*)d_in[1];   // (2, E): row = eidx, col = eidx + E
    const int*   batch  = (const int*)d_in[2];
    const float* emb    = (const float*)d_in[3];
    const float* conv_w = (const float*)d_in[4];
    const float* conv_b = (const float*)d_in[5];
    const float* w1     = (const float*)d_in[6];
    const float* b1     = (const float*)d_in[7];
    const float* w2     = (const float*)d_in[8];
    const float* b2     = (const float*)d_in[9];
    const float* w3     = (const float*)d_in[10];
    const float* b3     = (const float*)d_in[11];
    float* out = (float*)d_out;

    const int* row = eidx;
    const int* col = eidx + N_EDGES;

    // workspace layout (4-byte units)
    char* wsb = (char*)d_ws;
    size_t off = 0;
    auto alloc = [&](size_t elems) { void* p = wsb + off; off += ((elems * 4 + 255) & ~(size_t)255); return p; };
    int*      bcnt       = (int*)alloc(NBUCK);
    int*      bbase      = (int*)alloc(NBUCK + 1);
    int*      bcur       = (int*)alloc(NBUCK);
    int*      blkhist    = (int*)alloc((size_t)PART_BLOCKS * NBUCK);
    int*      row_start  = (int*)alloc(N_NODES);
    int*      degi       = (int*)alloc(N_NODES);
    float*    dinv       = (float*)alloc(N_NODES);
    unsigned* packed     = (unsigned*)alloc(N_NODES);
    float*    M          = (float*)alloc(VOCAB * H);
    int*      sorted_row = (int*)alloc(N_EDGES);
    float*    h          = (float*)alloc((size_t)N_NODES * H);
    unsigned short* t    = (unsigned short*)alloc((size_t)N_NODES * H / 2);  // bf16

    // packed staging (int[N_EDGES] = 12.8 MB) aliases t (dead until k_linear layer 1)
    int* staging = (int*)t;

    const int B = 256;
    const int gNH = (N_NODES * H + B - 1) / B;
    const int gLin = ((N_NODES + LIN_NODES_PER_WAVE - 1) / LIN_NODES_PER_WAVE * 64 + B - 1) / B;
    const int gG0 = (N_NODES + G0_NODES_PER_WAVE * 4 - 1) / (G0_NODES_PER_WAVE * 4);  // 3125

    hipLaunchKernelGGL(k_init, dim3((NBUCK + B - 1) / B), dim3(B), 0, stream, bcnt);
    hipLaunchKernelGGL(k_bhist, dim3(PART_BLOCKS), dim3(256), 0, stream, col, bcnt, blkhist);
    hipLaunchKernelGGL(k_bscan, dim3(1), dim3(1024), 0, stream, bcnt, bbase, bcur);
    hipLaunchKernelGGL(k_binA, dim3(PART_BLOCKS), dim3(1024), 0, stream,
                       row, col, blkhist, bcur, staging);
    hipLaunchKernelGGL(k_binB, dim3(NBUCK), dim3(256), 0, stream, staging, bbase, x,
                       sorted_row, degi, row_start, dinv, packed);

    // layer 0: vocabulary-factored
    hipLaunchKernelGGL(k_premix, dim3(VOCAB), dim3(H), 0, stream, emb, conv_w, M);
    hipLaunchKernelGGL(k_gather0, dim3(gG0), dim3(B), 0, stream,
                       sorted_row, row_start, degi, packed, M, dinv, conv_b, h);

    // layers 1,2
    for (int layer = 1; layer < N_LAYERS; ++layer) {
        hipLaunchKernelGGL(k_linear, dim3(gLin), dim3(B), 0, stream,
                           h, conv_w + (size_t)layer * H * H, dinv, t);
        hipLaunchKernelGGL(k_gather, dim3(gNH), dim3(B), 0, stream,
                           sorted_row, row_start, degi, t, dinv,
                           conv_b + (size_t)layer * H, h);
    }

    hipLaunchKernelGGL(k_poolmlp, dim3(N_GRAPHS), dim3(64), 0, stream,
                       h, batch, w1, b1, w2, b2, w3, b3, out);

    (void)in_sizes; (void)n_in; (void)out_size; (void)ws_size;
}